// Round 10
// baseline (221.705 us; speedup 1.0000x reference)
//
#include <hip/hip_runtime.h>
#include <math.h>

// VQ quantizer: z [N,64] fp32, codebook [512,64] fp32.
// out layout (all fp32): q_ste [N*64] | loss [1] | ids-as-float [N]
//
// R5: split-bf16 (hh+hl+lh) MFMA computes s = z.c - 0.5*|c|^2; rows with
// best-vs-runnerup margin > STH provably match the fp32 argmin; rest get an
// exact fp32 fallback. R8: 128KB LDS staging + dbuf prefetch -> engine 96us.
// R12: 3-dispatch split: main 108. R13: chunked fill + index-embedded exact
// top-2 scan (med3/max3 streaming, idx in low 4 mantissa bits): main 101,
// VALUBusy 36.5->26.8 BUT WRITE still 83MB (+15 vs ideal) and VGPR pinned
// 128: the HOT LOOP spills — live set was zh/zl 32 + dbuf frags 64 + gg 32
// + acc 32 + misc ~12 = ~172 vs 128 cap -> ~44 regs spilled/reloaded per
// tile. MfmaUtil 20.3 = exactly the 12-MFMA issue floor over the measured
// duration; 53% of cycles are scratch+LDS stalls at 2 waves/SIMD.
// R14 (this): fit 128 and double TLP.
//  - acc0 init direct from nhc2 LDS (uniform 64B broadcast) -> gg regs gone.
//  - single-buffered LDS_FRAGS -> second frag buffer gone. Live ~108 < 128.
//  - 1024-thr blocks (16 waves, grid 256, 2 row-iters): 4 waves/SIMD at
//    128 VGPR — TLP hides the per-tile LDS latency instead of the dbuf.
//  - fill = R9-verified 2-threads-per-codeword (shfl-combined c2).
//  - vq_fb + last-block finalize byte-identical to R12/R13 (verified).
//
// mfma_f32_32x32x16_bf16, A=codebook(M=32 cw), B=z(N=32 rows):
//   C/D: col=lane&31 (z-row), row=(reg&3)+8*(reg>>2)+4*(lane>>5) (codeword)
//   -> per-lane 16 accs are 16 codewords of the lane's OWN row.

constexpr int D     = 64;
constexpr int D4    = 16;      // float4s per row
constexpr int K     = 512;
constexpr float STH = 2e-4f;   // certainty margin in s-space (d-gap = 2*s-gap)

typedef __attribute__((ext_vector_type(8)))  short s16x8;
typedef __attribute__((ext_vector_type(16))) float f32x16;

#define FMA4(acc, zz, cc) do { \
  acc = fmaf((zz).x, (cc).x, acc); \
  acc = fmaf((zz).y, (cc).y, acc); \
  acc = fmaf((zz).z, (cc).z, acc); \
  acc = fmaf((zz).w, (cc).w, acc); } while (0)

#define MFMA_B(A, B, C) __builtin_amdgcn_mfma_f32_32x32x16_bf16(A, B, C, 0, 0, 0)

__device__ __forceinline__ unsigned short f2bf(float f) {
  unsigned u = __float_as_uint(f);
  return (unsigned short)((u + 0x7FFFu + ((u >> 16) & 1u)) >> 16);
}

// LDS map (dynamic, 133120 B):
//   [0,65536)       cbh frags:  addr = T*4096 + s*1024 + h*512 + col*16
//   [65536,131072)  cbl frags:  same order, +65536
//   [131072,133120) nhc2 floats, arranged[t*32 + h*16 + r] = -0.5*c2(perm)

#define LDS_FRAGS(CH, CL, T) do { \
  const int fb_ = (T) * 4096 + h * 512 + col * 16; \
  CH[0] = *(const s16x8*)(smem + fb_); \
  CH[1] = *(const s16x8*)(smem + fb_ + 1024); \
  CH[2] = *(const s16x8*)(smem + fb_ + 2048); \
  CH[3] = *(const s16x8*)(smem + fb_ + 3072); \
  CL[0] = *(const s16x8*)(smem + 65536 + fb_); \
  CL[1] = *(const s16x8*)(smem + 65536 + fb_ + 1024); \
  CL[2] = *(const s16x8*)(smem + 65536 + fb_ + 2048); \
  CL[3] = *(const s16x8*)(smem + 65536 + fb_ + 3072); \
} while (0)

// Exact streaming top-2 with index-embedded values (R13-verified).
// v' = (bits(v)&~15)|(15-r): <=15-ulp perturbation, absorbed by STH; sub-ulp
// ties are flagged -> exact fallback resolves. Per pair:
// t=med3(va,vb,m1); m1=max(max(va,vb),m1); m2=max(m2,t) == exact top-2.
#define TILE_BODY(T, CH, CL) do { \
  f32x16 acc0 = *(const f32x16*)(smem + 131072 + (((T) * 32 + h * 16) << 2)); \
  f32x16 acc1 = {}; \
  acc0 = MFMA_B(CH[0], zh[0], acc0);  acc1 = MFMA_B(CH[1], zh[1], acc1); \
  acc0 = MFMA_B(CH[2], zh[2], acc0);  acc1 = MFMA_B(CH[3], zh[3], acc1); \
  acc0 = MFMA_B(CH[0], zl[0], acc0);  acc1 = MFMA_B(CH[1], zl[1], acc1); \
  acc0 = MFMA_B(CH[2], zl[2], acc0);  acc1 = MFMA_B(CH[3], zl[3], acc1); \
  acc0 = MFMA_B(CL[0], zh[0], acc0);  acc1 = MFMA_B(CL[1], zh[1], acc1); \
  acc0 = MFMA_B(CL[2], zh[2], acc0);  acc1 = MFMA_B(CL[3], zh[3], acc1); \
  const unsigned m1pre_bits = __float_as_uint(m1); \
  _Pragma("unroll") \
  for (int rp = 0; rp < 8; ++rp) { \
    float va = acc0[2 * rp]     + acc1[2 * rp]; \
    float vb = acc0[2 * rp + 1] + acc1[2 * rp + 1]; \
    va = __uint_as_float((__float_as_uint(va) & 0xFFFFFFF0u) \
                         | (unsigned)(15 - 2 * rp)); \
    vb = __uint_as_float((__float_as_uint(vb) & 0xFFFFFFF0u) \
                         | (unsigned)(14 - 2 * rp)); \
    float tmid = __builtin_amdgcn_fmed3f(va, vb, m1); \
    m1 = fmaxf(fmaxf(va, vb), m1); \
    m2 = fmaxf(m2, tmid); \
  } \
  if (__float_as_uint(m1) != m1pre_bits) tbest = (T); \
} while (0)

__global__ __launch_bounds__(1024)
void vq_main(const float* __restrict__ z, const float* __restrict__ cbk,
             float* __restrict__ out, float* __restrict__ lossAcc,
             unsigned* __restrict__ cnt, unsigned* __restrict__ list, int N)
{
  extern __shared__ char smem[];

  const int tid  = threadIdx.x;
  const int lane = tid & 63;
  const int wave = tid >> 6;
  const int col  = lane & 31;    // this lane's z-row within the wave's 32 rows
  const int h    = lane >> 5;    // k-half / output split

  // ---- fill: convert codebook -> bf16 hi/lo frag-order tables + nhc2 ------
  // two threads per codeword: cw = tid>>1, dims [32*(tid&1), +32). R9-verified.
  {
    const int cw   = tid >> 1;
    const int half = tid & 1;
    const float4* c4 = (const float4*)(cbk + (size_t)cw * D) + half * 8;
    float4 f[8];
    #pragma unroll
    for (int i = 0; i < 8; ++i) f[i] = c4[i];
    float pc2 = 0.f;
    #pragma unroll
    for (int i = 0; i < 8; ++i) FMA4(pc2, f[i], f[i]);
    float e[32];
    #pragma unroll
    for (int i = 0; i < 8; ++i) {
      e[4*i] = f[i].x; e[4*i+1] = f[i].y; e[4*i+2] = f[i].z; e[4*i+3] = f[i].w;
    }
    const int T = cw >> 5, cc = cw & 31;
    #pragma unroll
    for (int sl = 0; sl < 2; ++sl) {
      #pragma unroll
      for (int h2 = 0; h2 < 2; ++h2) {
        const int ld0 = sl * 16 + h2 * 8;
        s16x8 vh, vl;
        #pragma unroll
        for (int j = 0; j < 8; ++j) {
          unsigned short hb = f2bf(e[ld0 + j]);
          float hf = __uint_as_float((unsigned)hb << 16);
          vh[j] = (short)hb;
          vl[j] = (short)f2bf(e[ld0 + j] - hf);
        }
        const int a = T * 4096 + (2 * half + sl) * 1024 + h2 * 512 + cc * 16;
        *(s16x8*)(smem + a) = vh;
        *(s16x8*)(smem + 65536 + a) = vl;
      }
    }
    float c2full = pc2 + __shfl_xor(pc2, 1, 64);  // lo+hi on half==0 thread
    if (half == 0) {
      // invert perm(r,h) = (r&3) + 8*(r>>2) + 4*h : arranged[t*32 + h*16 + r]
      const int ai = (T << 5) + (((cc >> 2) & 1) << 4) + ((cc >> 3) << 2) + (cc & 3);
      *(float*)(smem + 131072 + ai * 4) = -0.5f * c2full;
    }
  }
  __syncthreads();   // tables read-only afterwards: no more barriers

  float lacc = 0.f;

  #pragma unroll 1
  for (int it = 0; it < 2; ++it) {
    const long rowg = (long)blockIdx.x * 1024 + it * 512 + wave * 32 + col;

    // z row -> bf16 hi/lo B-frags. Lane holds k = 16s + 8h + j, j=0..7.
    const float4* zp4 = (const float4*)(z + (size_t)rowg * D);
    s16x8 zh[4], zl[4];
    #pragma unroll
    for (int s = 0; s < 4; ++s) {
      float4 p0 = zp4[4 * s + 2 * h];
      float4 p1 = zp4[4 * s + 2 * h + 1];
      float e[8] = {p0.x, p0.y, p0.z, p0.w, p1.x, p1.y, p1.z, p1.w};
      #pragma unroll
      for (int j = 0; j < 8; ++j) {
        unsigned short hb = f2bf(e[j]);
        float hf = __uint_as_float((unsigned)hb << 16);
        zh[s][j] = (short)hb;
        zl[s][j] = (short)f2bf(e[j] - hf);
      }
    }

    float m1 = -INFINITY, m2 = -INFINITY;
    int tbest = 0;

    // single-buffered frags: 4 waves/SIMD covers the per-tile LDS latency.
    #pragma unroll 1
    for (int t = 0; t < 16; ++t) {
      s16x8 ch[4], cl[4];
      LDS_FRAGS(ch, cl, t);
      TILE_BODY(t, ch, cl);
    }

    // winner r from the embedded bits; cw = (tbest<<5) + perm(r,h)
    const int rbest = 15 - (int)(__float_as_uint(m1) & 15u);
    int idx = (tbest << 5) + (h << 2) + (rbest & 3) + ((rbest >> 2) << 3);

    // combine the two k-halves (lane <-> lane^32); lower cw wins ties
    float om1  = __shfl_xor(m1, 32);
    float om2  = __shfl_xor(m2, 32);
    int   oidx = __shfl_xor(idx, 32);
    float nm2 = fmaxf(fminf(m1, om1), fmaxf(m2, om2));
    bool take = (om1 > m1) || ((om1 == m1) && (oidx < idx));
    if (take) { m1 = om1; idx = oidx; }
    m2 = nm2;

    if (m1 - m2 > STH) {
      // certain: provably the fp32 argmin. Epilogue ops identical to R4,
      // split across the lane pair (h picks the 32-element half of the row).
      const float4* qp = (const float4*)(cbk + (size_t)idx * D) + (h << 3);
      const float4* zp = (const float4*)(z + (size_t)rowg * D) + (h << 3);
      float4*       op = (float4*)(out + (size_t)rowg * D) + (h << 3);
      #pragma unroll
      for (int i = 0; i < 8; ++i) {
        float4 q = qp[i], zz = zp[i], u, qs;
        u.x = q.x - zz.x; u.y = q.y - zz.y; u.z = q.z - zz.z; u.w = q.w - zz.w;
        qs.x = zz.x + u.x; qs.y = zz.y + u.y; qs.z = zz.z + u.z; qs.w = zz.w + u.w;
        FMA4(lacc, u, u);
        op[i] = qs;
      }
      if (h == 0) (out + (size_t)N * D + 1)[rowg] = (float)idx;
    } else if (h == 0) {
      unsigned p = atomicAdd(cnt, 1u);     // flagged -> exact fallback kernel
      list[p] = (unsigned)rowg;
    }
  }

  // loss (certain rows): wave shuffle reduce -> one atomicAdd per wave.
  #pragma unroll
  for (int off = 32; off > 0; off >>= 1) lacc += __shfl_down(lacc, off, 64);
  if (lane == 0) atomicAdd(lossAcc, lacc);
}

// ---------------- fallback + finalize: wave-per-row exact R4 chains ---------
// Lane handles 8 consecutive codewords (k = lane*8+j); per-(row,k) the FMA
// chains are BIT-IDENTICAL to R4/R7 (c2: FMA4 over 16 float4s in order; dot:
// a0=even chunks / b0=odd chunks in order; d = fmaf(-2,dot,z2)+c2).
// Cross-lane merge keeps min-d, tie -> lowest k == numpy first-min.
// Loss finalized by the last B-block (A's adds visible by stream order).
__global__ __launch_bounds__(256)
void vq_fb(const float* __restrict__ z, const float* __restrict__ cbk,
           float* __restrict__ out, float* __restrict__ lossAcc,
           const unsigned* __restrict__ list, const unsigned* __restrict__ cntp,
           unsigned* __restrict__ done, int N)
{
  const unsigned cnt = *cntp;
  const int tid  = threadIdx.x;
  const int lane = tid & 63;
  const unsigned wid = (blockIdx.x * blockDim.x + tid) >> 6;
  const unsigned nw  = (gridDim.x * blockDim.x) >> 6;

  float lacc = 0.f;
  #pragma unroll 1
  for (unsigned p = wid; p < cnt; p += nw) {
    const size_t r0 = (size_t)list[p];

    const float4* zp = (const float4*)(z + r0 * D);
    float4 z0[D4];
    #pragma unroll
    for (int i = 0; i < D4; ++i) z0[i] = zp[i];
    float z2 = 0.f;
    #pragma unroll
    for (int i = 0; i < D4; ++i) FMA4(z2, z0[i], z0[i]);

    float best = INFINITY;
    int   bi = 0;
    #pragma unroll 1
    for (int j = 0; j < 8; ++j) {
      const int k = (lane << 3) + j;
      const float4* c4 = (const float4*)(cbk + (size_t)k * D);
      float4 cr[D4];
      #pragma unroll
      for (int i = 0; i < D4; ++i) cr[i] = c4[i];
      float c2 = 0.f;
      #pragma unroll
      for (int i = 0; i < D4; ++i) FMA4(c2, cr[i], cr[i]);
      float a0 = 0.f, b0 = 0.f;
      #pragma unroll
      for (int i = 0; i < 8; ++i) {
        FMA4(a0, z0[2 * i],     cr[2 * i]);
        FMA4(b0, z0[2 * i + 1], cr[2 * i + 1]);
      }
      float dot = a0 + b0;
      float d = fmaf(-2.f, dot, z2) + c2;
      if (d < best) { best = d; bi = k; }   // strict <, ascending k
    }

    #pragma unroll
    for (int off = 32; off > 0; off >>= 1) {
      float ob = __shfl_xor(best, off, 64);
      int  obi = __shfl_xor(bi, off, 64);
      if (ob < best || (ob == best && obi < bi)) { best = ob; bi = obi; }
    }

    if (lane == 0) {
      const float4* qp = (const float4*)(cbk + (size_t)bi * D);
      float4* o = (float4*)(out + r0 * D);
      #pragma unroll
      for (int i = 0; i < D4; ++i) {
        float4 q = qp[i], zz = z0[i], u, qs;
        u.x = q.x - zz.x; u.y = q.y - zz.y; u.z = q.z - zz.z; u.w = q.w - zz.w;
        qs.x = zz.x + u.x; qs.y = zz.y + u.y; qs.z = zz.z + u.z; qs.w = zz.w + u.w;
        FMA4(lacc, u, u);
        o[i] = qs;
      }
      (out + (size_t)N * D + 1)[r0] = (float)bi;
    }
  }

  // add this kernel's loss contributions, then last block finalizes
  #pragma unroll
  for (int off = 32; off > 0; off >>= 1) lacc += __shfl_down(lacc, off, 64);
  __shared__ float wsum[4];
  if (lane == 0) wsum[tid >> 6] = lacc;
  __syncthreads();
  if (tid == 0) {
    float s = wsum[0] + wsum[1] + wsum[2] + wsum[3];
    if (s != 0.f) atomicAdd(lossAcc, s);
    __threadfence();                               // publish before done-add
    unsigned d = atomicAdd(done, 1u);
    if (d == gridDim.x - 1) {                      // last block: all adds done
      float total = atomicAdd(lossAcc, 0.0f);      // device-scope atomic read
      out[(size_t)N * D] = 1.25f * (total / (float)((long)N * D));
    }
  }
}

extern "C" void kernel_launch(void* const* d_in, const int* in_sizes, int n_in,
                              void* d_out, int out_size, void* d_ws, size_t ws_size,
                              hipStream_t stream)
{
  const float* z   = (const float*)d_in[0];
  const float* cbk = (const float*)d_in[1];
  float* out = (float*)d_out;
  float* ws  = (float*)d_ws;
  const int N = in_sizes[0] / D;

  // ws layout (floats): [0]=lossAcc, [1]=flagCount, [2]=done, [64..)=flag list
  float*    lossAcc = ws;
  unsigned* cnt     = (unsigned*)(ws + 1);
  unsigned* done    = (unsigned*)(ws + 2);
  unsigned* list    = (unsigned*)(ws + 64);

  hipMemsetAsync(ws, 0, 12, stream);  // clears lossAcc + flagCount + done
  vq_main<<<N / 1024, 1024, 133120, stream>>>(z, cbk, out, lossAcc, cnt, list, N);
  vq_fb<<<512, 256, 0, stream>>>(z, cbk, out, lossAcc, list, cnt, done, N);
}